// Round 8
// baseline (518.942 us; speedup 1.0000x reference)
//
#include <hip/hip_runtime.h>

// Problem constants (from reference):
//   B=100000, R1=1, N1=200, N2=200, N3=50, R2=32
//   TT_core: (1,200,200,50,32) f32  = 64,000,000 elems (256 MB)
//   K1,K2: (200,200) f32; K3: (50,50) f32; indices: (B,3) int (values in [0,50))
//   out = (T3 gathered)[B,1,32] (3.2M f32), reg = T3*TT (64M f32)
// d_out layout: [0,3.2M) out, [3.2M, 67.2M) reg.
//
// Round-8: contract-k becomes an MFMA GEMM D[s,c] = sum_k T2[ab,k,s]*K3[c,k]
// with s=row / c=col so each lane's 4 acc values are s-contiguous ->
// dwordx4 TT-read + dwordx4 reg-write. K3 pre-packed to fp16 B-fragments
// (zero-padded 64x64), staged in 8 KB LDS. Round-7 evidence: ck was the
// leader at 187us with 39% VALU (2500 scalar FMA/thread) + 150 scalar vmem.

typedef float    f32x4 __attribute__((ext_vector_type(4)));
typedef float    f32x8 __attribute__((ext_vector_type(8)));
typedef _Float16 half8 __attribute__((ext_vector_type(8)));
typedef unsigned short u16;
typedef unsigned int   u32;

#define N12   200
#define N3    50
#define R2    32
#define SJK   320000          // stride of i in TT == N2*N3*R2; also stride of a in T1
#define SKS   1600            // stride of j / b  == N3*R2
#define NTOT  64000000
#define OUT_ELEMS 3200000     // B*32
#define APAD  208             // padded rows of K matrices (13 * 16)
#define KPAD  224             // padded contraction dim (7 * 32)
#define K3B_HALVES 4096       // 2 kstep * 4 csub * 64 lane * 8 e

// ---------------- prep: K1,K2 -> padded fp16 [208][224]; K3 -> B-frag pack --
// kh: K1 at 0, K2 at APAD*KPAD, K3B (fragment-ordered fp16) at 2*APAD*KPAD.
// K3B[u], u = ((kstep*4+csub)*64 + lane)*8 + e  holds K3[c,k] with
// c = csub*16 + (lane&15), k = kstep*32 + (lane>>4)*8 + e  (0 if c/k >= 50).
__global__ __launch_bounds__(256) void k_prep(
    const float* __restrict__ K1, const float* __restrict__ K2,
    const float* __restrict__ K3, u16* __restrict__ kh) {
  int t = blockIdx.x * 256 + threadIdx.x;
  const int total = APAD * KPAD;
  if (t >= 2 * total + K3B_HALVES) return;
  float x;
  if (t < 2 * total) {
    const float* src = (t < total) ? K1 : K2;
    int tt = (t < total) ? t : t - total;
    int r = tt / KPAD, c = tt % KPAD;
    x = (r < N12 && c < N12) ? src[r * N12 + c] : 0.f;
  } else {
    int u = t - 2 * total;
    int e = u & 7, l = (u >> 3) & 63, frag = u >> 9;   // frag = kstep*4+csub
    int c = (frag & 3) * 16 + (l & 15);
    int k = (frag >> 2) * 32 + (l >> 4) * 8 + e;
    x = (c < N3 && k < N3) ? K3[c * N3 + k] : 0.f;
  }
  kh[t] = __builtin_bit_cast(u16, (_Float16)x);
}

// ---------------- MFMA contraction: D[row,n] = sum_k K[row,k] * B[k,n] -----
// (unchanged from round 7; see notes there)
#define ALOAD(S)                                                              \
  { ar0 = *(const int4*)(Ah + ((wave*4+0)*16 + arow) * KPAD + (S)*32 + acolh); \
    ar1 = *(const int4*)(Ah + ((wave*4+1)*16 + arow) * KPAD + (S)*32 + acolh); \
    ar2 = *(const int4*)(Ah + ((wave*4+2)*16 + arow) * KPAD + (S)*32 + acolh); \
    ar3 = *(const int4*)(Ah + ((wave*4+3)*16 + arow) * KPAD + (S)*32 + acolh); }

#define ASTORE(BUF)                                                           \
  { *(int4*)(&As[BUF][(wave*4+0)*512 + lane*8]) = ar0;                        \
    *(int4*)(&As[BUF][(wave*4+1)*512 + lane*8]) = ar1;                        \
    *(int4*)(&As[BUF][(wave*4+2)*512 + lane*8]) = ar2;                        \
    *(int4*)(&As[BUF][(wave*4+3)*512 + lane*8]) = ar3; }

#define LOADB(S, BV)                                                          \
  { _Pragma("unroll")                                                         \
    for (int e = 0; e < 8; ++e) {                                             \
      int kr = (S)*32 + kq + e; if (kr > 199) kr = 199;                       \
      BV[e] = bp[(long)kr * ldB]; } }

#define STAGE(S, BV)                                                          \
  { half8 bh;                                                                 \
    _Pragma("unroll")                                                         \
    for (int e = 0; e < 8; ++e) bh[e] = (_Float16)BV[e];                      \
    const u16* as_ = &As[(S)&1][0];                                           \
    _Pragma("unroll")                                                         \
    for (int t = 0; t < 13; ++t) {                                            \
      half8 ah = *(const half8*)(as_ + (t*16 + l15)*32 + kq);                 \
      acc[t] = __builtin_amdgcn_mfma_f32_16x16x32_f16(ah, bh, acc[t], 0,0,0); \
    } }

__global__ __launch_bounds__(256, 3) void k_mfma_contract(
    const float* __restrict__ Bsrc, const u16* __restrict__ Ah,
    float* __restrict__ Dout, int ldB, int ldD, long bStrideB, long bStrideD) {
  __shared__ __align__(16) u16 As[2][8192];   // 2 x 16 KB
  const int lane = threadIdx.x & 63;
  const int wave = threadIdx.x >> 6;
  const int l15  = lane & 15;
  const int kg   = lane >> 4;
  const int kq   = kg * 8;
  const int arow = lane >> 2;           // 0..15 within a 16-row chunk
  const int acolh = (lane & 3) * 8;     // halves
  const int n0   = blockIdx.x * 64 + wave * 16 + l15;
  const long bb  = (long)blockIdx.y * bStrideB;
  const long db  = (long)blockIdx.y * bStrideD;
  const float* bp = Bsrc + bb + n0;

  f32x4 acc[13];
#pragma unroll
  for (int t = 0; t < 13; ++t)
#pragma unroll
    for (int q = 0; q < 4; ++q) acc[t][q] = 0.f;

  int4 ar0, ar1, ar2, ar3;
  f32x8 B0, B1, B2, B3, B4, B5, B6;

  // prologue: A-slice 0 + ALL B loads; single drain at first barrier
  ALOAD(0)
  LOADB(0, B0) LOADB(1, B1) LOADB(2, B2) LOADB(3, B3)
  LOADB(4, B4) LOADB(5, B5) LOADB(6, B6)
  ASTORE(0)
  __syncthreads();

  ALOAD(1)  STAGE(0, B0)  ASTORE(1)  __syncthreads();
  ALOAD(2)  STAGE(1, B1)  ASTORE(0)  __syncthreads();
  ALOAD(3)  STAGE(2, B2)  ASTORE(1)  __syncthreads();
  ALOAD(4)  STAGE(3, B3)  ASTORE(0)  __syncthreads();
  ALOAD(5)  STAGE(4, B4)  ASTORE(1)  __syncthreads();
  ALOAD(6)  STAGE(5, B5)  ASTORE(0)  __syncthreads();
  STAGE(6, B6)

#pragma unroll
  for (int t = 0; t < 13; ++t) {
    const int rb = t * 16 + kg * 4;
#pragma unroll
    for (int r = 0; r < 4; ++r) {
      const int row = rb + r;
      if (row < N12) Dout[db + (long)row * ldD + n0] = acc[t][r];
    }
  }
}

// ------- contract k + elementwise, MFMA form ------------------------------
// Per wave: one ab pair. D[s,c] = sum_k A[s,k]*B[k,c], A[s,k]=T2[ab,k,s]
// (fp16 on the fly), B = K3B fragments from LDS. D lane layout: col c =
// csub*16 + (l&15), rows s = rt*16 + (l>>4)*4 + r -> r is s-contiguous =>
// dwordx4 TT read + dwordx4 reg write.
__global__ __launch_bounds__(256, 4) void k_contract_k_mfma(
    const float* __restrict__ T2, const float* __restrict__ TT,
    const u16* __restrict__ K3B, float* __restrict__ reg) {
  __shared__ __align__(16) u16 bs[K3B_HALVES];   // 8 KB
  const int tid  = threadIdx.x;
  {
    const int4* src = (const int4*)K3B;
    int4* dst = (int4*)bs;
    dst[tid] = src[tid];
    dst[tid + 256] = src[tid + 256];
  }
  const int lane = tid & 63;
  const int wave = tid >> 6;
  const int l15  = lane & 15;
  const int kg   = lane >> 4;
  const int ab   = blockIdx.x * 4 + wave;         // 0..39999
  const int base = ab * SKS;
  __syncthreads();

  // B-fragments (all 8) from LDS
  half8 bf[2][4];
#pragma unroll
  for (int ks = 0; ks < 2; ++ks)
#pragma unroll
    for (int cs = 0; cs < 4; ++cs)
      bf[ks][cs] = *(const half8*)(bs + ((ks * 4 + cs) * 64 + lane) * 8);

  // A loads: af[rt][ks][e] = T2[ab, k, s], k = ks*32+kg*8+e (clamped; B rows
  // >=50 are zero so clamped garbage contributes 0), s = rt*16+l15.
  float af[2][2][8];
#pragma unroll
  for (int rt = 0; rt < 2; ++rt)
#pragma unroll
    for (int ks = 0; ks < 2; ++ks)
#pragma unroll
      for (int e = 0; e < 8; ++e) {
        int k = ks * 32 + kg * 8 + e; if (k > 49) k = 49;
        af[rt][ks][e] = T2[base + k * R2 + rt * 16 + l15];
      }

  f32x4 acc[2][4];
#pragma unroll
  for (int rt = 0; rt < 2; ++rt)
#pragma unroll
    for (int cs = 0; cs < 4; ++cs)
#pragma unroll
      for (int q = 0; q < 4; ++q) acc[rt][cs][q] = 0.f;

#pragma unroll
  for (int rt = 0; rt < 2; ++rt)
#pragma unroll
    for (int ks = 0; ks < 2; ++ks) {
      half8 ah;
#pragma unroll
      for (int e = 0; e < 8; ++e) ah[e] = (_Float16)af[rt][ks][e];
#pragma unroll
      for (int cs = 0; cs < 4; ++cs)
        acc[rt][cs] = __builtin_amdgcn_mfma_f32_16x16x32_f16(ah, bf[ks][cs], acc[rt][cs], 0, 0, 0);
    }

  // epilogue: c = cs*16+l15 (valid < 50), s0 = rt*16+kg*4; dwordx4 TT+store
#pragma unroll
  for (int rt = 0; rt < 2; ++rt)
#pragma unroll
    for (int cs = 0; cs < 4; ++cs) {
      const int c = cs * 16 + l15;
      if (c < N3) {
        const int o = base + c * R2 + rt * 16 + kg * 4;
        f32x4 tv = *(const f32x4*)(TT + o);
        f32x4 r;
#pragma unroll
        for (int q = 0; q < 4; ++q) r[q] = acc[rt][cs][q] * tv[q];
        *(f32x4*)(reg + o) = r;
      }
    }
}

// ---------------- fallback path helpers (unused when ws >= 256 MB) ---------
__global__ __launch_bounds__(256) void k_transpose(
    const float* __restrict__ K2, float* __restrict__ K2T) {
  int t = blockIdx.x * 256 + threadIdx.x;
  if (t < N12 * N12) {
    int i = t / N12, a = t % N12;
    K2T[t] = K2[a * N12 + i];
  }
}

__global__ __launch_bounds__(256) void k_contract_j_inplace(
    float* T12, const float* __restrict__ K2T) {
  __shared__ float lds[N12 * 80];   // 64000 B
  const int a    = blockIdx.y;
  const int m0   = blockIdx.x * 80;
  const int base = a * SJK + m0;
  for (int t = threadIdx.x; t < N12 * 80; t += 256) {
    int j = t / 80, ml = t % 80;
    lds[t] = T12[base + j * SKS + ml];
  }
  __syncthreads();
  for (int o = threadIdx.x; o < N12 * 80; o += 256) {
    int b = o / 80, ml = o % 80;
    float acc = 0.f;
#pragma unroll 4
    for (int j = 0; j < N12; ++j)
      acc = fmaf(K2T[j * N12 + b], lds[j * 80 + ml], acc);
    T12[base + b * SKS + ml] = acc;
  }
}

// ------------- gather: out[n,s] = sum_k K3[c,k] * T2[a,b,k,s]  (a,b,c < 50)
__global__ __launch_bounds__(256) void k_gather(
    const float* T2, const float* __restrict__ K3,
    const int* __restrict__ idx, float* __restrict__ out) {
  int g = blockIdx.x * 256 + threadIdx.x;   // 3.2M threads exactly
  int n = g >> 5, s = g & 31;
  int a = idx[n * 3 + 0], b = idx[n * 3 + 1], c = idx[n * 3 + 2];
  const float* t2  = T2 + a * SJK + b * SKS + s;
  const float* k3r = K3 + c * N3;
  float acc = 0.f;
#pragma unroll
  for (int k = 0; k < N3; ++k) acc = fmaf(k3r[k], t2[k * R2], acc);
  out[g] = acc;
}

// ------- scalar contract-k (fallback path only) ---------------------------
__global__ __launch_bounds__(256) void k_contract_k_reg(
    const float* T2, const float* __restrict__ TT,
    const float* __restrict__ K3, float* reg) {
  const int t  = blockIdx.x * 256 + threadIdx.x;
  const int s  = t & 31;
  const int ab = t >> 5;
  const int base = ab * SKS + s;
  float v[N3];
#pragma unroll
  for (int k = 0; k < N3; ++k) v[k] = T2[base + k * R2];
  for (int c = 0; c < N3; ++c) {
    const float* k3r = K3 + c * N3;
    float a0 = 0.f, a1 = 0.f, a2 = 0.f, a3 = 0.f;
#pragma unroll
    for (int k = 0; k < 48; k += 4) {
      a0 = fmaf(k3r[k],     v[k],     a0);
      a1 = fmaf(k3r[k + 1], v[k + 1], a1);
      a2 = fmaf(k3r[k + 2], v[k + 2], a2);
      a3 = fmaf(k3r[k + 3], v[k + 3], a3);
    }
    a0 = fmaf(k3r[48], v[48], a0);
    a1 = fmaf(k3r[49], v[49], a1);
    const int o = base + c * R2;
    reg[o] = ((a0 + a1) + (a2 + a3)) * TT[o];
  }
}

extern "C" void kernel_launch(void* const* d_in, const int* in_sizes, int n_in,
                              void* d_out, int out_size, void* d_ws, size_t ws_size,
                              hipStream_t stream) {
  const float* TT  = (const float*)d_in[0];
  const float* K1  = (const float*)d_in[1];
  const float* K2  = (const float*)d_in[2];
  const float* K3  = (const float*)d_in[3];
  const int*   idx = (const int*)d_in[4];

  float* out = (float*)d_out;          // [0, 3.2M)
  float* reg = out + OUT_ELEMS;        // [3.2M, 67.2M) -- also T1 scratch
  // Prepped fp16 K matrices + K3B fragment pack live at the start of the out
  // region (dead by the time k_gather overwrites out). A-staging overruns
  // read a few KB past kh -- still inside d_out, benign.
  u16* kh = (u16*)d_out;
  const int matoff = APAD * KPAD;               // K2 offset within kh
  const u16* k3b = kh + 2 * matoff;             // K3B offset

  k_prep<<<dim3((2 * matoff + K3B_HALVES + 255) / 256), 256, 0, stream>>>(
      K1, K2, K3, kh);

  // contract i: T1[a,m] = sum_i K1[a,i]*TT[i,m]  -> reg region
  k_mfma_contract<<<dim3(SJK / 64, 1), 256, 0, stream>>>(
      TT, kh, reg, SJK, SJK, 0L, 0L);

  const size_t need = (size_t)NTOT * sizeof(float);   // 256,000,000 B
  if (ws_size >= need) {
    float* T2 = (float*)d_ws;
    // contract j (batched over a): T2[a,b,m2] = sum_j K2[b,j]*T1[a,j,m2]
    k_mfma_contract<<<dim3(SKS / 64, N12), 256, 0, stream>>>(
        reg, kh + matoff, T2, SKS, SKS, (long)SJK, (long)SJK);
    // contract k BEFORE gather (k3b lives in out region; gather clobbers it)
    k_contract_k_mfma<<<dim3(40000 / 4), 256, 0, stream>>>(T2, TT, k3b, reg);
    k_gather<<<dim3(OUT_ELEMS / 256), 256, 0, stream>>>(T2, K3, idx, out);
  } else {
    // in-place fallback (never taken on this harness: rounds 1-7 ran ws path)
    float* k2t = out + 2 * OUT_ELEMS / 32;  // scratch inside out region
    k_transpose<<<dim3((N12 * N12 + 255) / 256), 256, 0, stream>>>(K2, k2t);
    k_contract_j_inplace<<<dim3(20, N12), 256, 0, stream>>>(reg, k2t);
    k_gather<<<dim3(OUT_ELEMS / 256), 256, 0, stream>>>(reg, K3, idx, out);
    k_contract_k_reg<<<dim3(40000 * 32 / 256), 256, 0, stream>>>(reg, TT, K3, reg);
  }
}

// Round 9
// 445.787 us; speedup vs baseline: 1.1641x; 1.1641x over previous
//
#include <hip/hip_runtime.h>
#include <type_traits>

// Problem constants (from reference):
//   B=100000, R1=1, N1=200, N2=200, N3=50, R2=32
//   TT_core: (1,200,200,50,32) f32  = 64,000,000 elems (256 MB)
//   K1,K2: (200,200) f32; K3: (50,50) f32; indices: (B,3) int (values in [0,50))
//   out = (T3 gathered)[B,1,32] (3.2M f32), reg = T3*TT (64M f32)
// d_out layout: [0,3.2M) out, [3.2M, 67.2M) reg.
//
// Round-9: T1/T2 stored as fp16 (numerically free: values were already
// RTE-rounded at the consuming MFMA operand; only the gather sees new
// quantization, ~1 abs on |out|~1400). Pipeline ideal traffic 1.82 GB ->
// 1.31 GB. ck occupancy 4 -> 8 waves/SIMD (round-8: 46% HBM, all else idle,
// VGPR 44 -> latency-bound at 4 waves).

typedef float    f32x4 __attribute__((ext_vector_type(4)));
typedef float    f32x8 __attribute__((ext_vector_type(8)));
typedef _Float16 half8 __attribute__((ext_vector_type(8)));
typedef unsigned short ushort8 __attribute__((ext_vector_type(8)));
typedef unsigned short u16;
typedef unsigned int   u32;

#define N12   200
#define N3    50
#define R2    32
#define SJK   320000          // stride of i in TT == N2*N3*R2; also stride of a in T1
#define SKS   1600            // stride of j / b  == N3*R2
#define NTOT  64000000
#define OUT_ELEMS 3200000     // B*32
#define APAD  208             // padded rows of K matrices (13 * 16)
#define KPAD  224             // padded contraction dim (7 * 32)
#define K3B_HALVES 4096       // 2 kstep * 4 csub * 64 lane * 8 e

// ---------------- prep: K1,K2 -> padded fp16 [208][224]; K3 -> B-frag pack --
// kh: K1 at 0, K2 at APAD*KPAD, K3B (fragment-ordered fp16) at 2*APAD*KPAD.
__global__ __launch_bounds__(256) void k_prep(
    const float* __restrict__ K1, const float* __restrict__ K2,
    const float* __restrict__ K3, u16* __restrict__ kh) {
  int t = blockIdx.x * 256 + threadIdx.x;
  const int total = APAD * KPAD;
  if (t >= 2 * total + K3B_HALVES) return;
  float x;
  if (t < 2 * total) {
    const float* src = (t < total) ? K1 : K2;
    int tt = (t < total) ? t : t - total;
    int r = tt / KPAD, c = tt % KPAD;
    x = (r < N12 && c < N12) ? src[r * N12 + c] : 0.f;
  } else {
    int u = t - 2 * total;
    int e = u & 7, l = (u >> 3) & 63, frag = u >> 9;   // frag = kstep*4+csub
    int c = (frag & 3) * 16 + (l & 15);
    int k = (frag >> 2) * 32 + (l >> 4) * 8 + e;
    x = (c < N3 && k < N3) ? K3[c * N3 + k] : 0.f;
  }
  kh[t] = __builtin_bit_cast(u16, (_Float16)x);
}

// ---------------- MFMA contraction: D[row,n] = sum_k K[row,k] * B[k,n] -----
// Templated on B element type (float: cvt at stage; u16: raw fp16) and D
// element type (float / u16-fp16 store). A via LDS dbuf (lgkmcnt), B fully
// prefetched in regs (single vmcnt drain) -- round-7 structure.
#define ALOAD(S)                                                              \
  { ar0 = *(const int4*)(Ah + ((wave*4+0)*16 + arow) * KPAD + (S)*32 + acolh); \
    ar1 = *(const int4*)(Ah + ((wave*4+1)*16 + arow) * KPAD + (S)*32 + acolh); \
    ar2 = *(const int4*)(Ah + ((wave*4+2)*16 + arow) * KPAD + (S)*32 + acolh); \
    ar3 = *(const int4*)(Ah + ((wave*4+3)*16 + arow) * KPAD + (S)*32 + acolh); }

#define ASTORE(BUF)                                                           \
  { *(int4*)(&As[BUF][(wave*4+0)*512 + lane*8]) = ar0;                        \
    *(int4*)(&As[BUF][(wave*4+1)*512 + lane*8]) = ar1;                        \
    *(int4*)(&As[BUF][(wave*4+2)*512 + lane*8]) = ar2;                        \
    *(int4*)(&As[BUF][(wave*4+3)*512 + lane*8]) = ar3; }

#define LOADB(S, BV)                                                          \
  { _Pragma("unroll")                                                         \
    for (int e = 0; e < 8; ++e) {                                             \
      int kr = (S)*32 + kq + e; if (kr > 199) kr = 199;                       \
      BV[e] = bp[(long)kr * ldB]; } }

#define STAGE(S, BV)                                                          \
  { half8 bh;                                                                 \
    _Pragma("unroll")                                                         \
    for (int e = 0; e < 8; ++e) {                                             \
      if constexpr (BF32) bh[e] = (_Float16)BV[e];                            \
      else bh[e] = __builtin_bit_cast(_Float16, (u16)BV[e]);                  \
    }                                                                         \
    const u16* as_ = &As[(S)&1][0];                                           \
    _Pragma("unroll")                                                         \
    for (int t = 0; t < 13; ++t) {                                            \
      half8 ah = *(const half8*)(as_ + (t*16 + l15)*32 + kq);                 \
      acc[t] = __builtin_amdgcn_mfma_f32_16x16x32_f16(ah, bh, acc[t], 0,0,0); \
    } }

template <typename BT, typename DT>
__global__ __launch_bounds__(256, 3) void k_mfma_contract(
    const BT* __restrict__ Bsrc, const u16* __restrict__ Ah,
    DT* __restrict__ Dout, int ldB, int ldD, long bStrideB, long bStrideD) {
  constexpr bool BF32 = std::is_same_v<BT, float>;
  __shared__ __align__(16) u16 As[2][8192];   // 2 x 16 KB
  const int lane = threadIdx.x & 63;
  const int wave = threadIdx.x >> 6;
  const int l15  = lane & 15;
  const int kg   = lane >> 4;
  const int kq   = kg * 8;
  const int arow = lane >> 2;           // 0..15 within a 16-row chunk
  const int acolh = (lane & 3) * 8;     // halves
  const int n0   = blockIdx.x * 64 + wave * 16 + l15;
  const long bb  = (long)blockIdx.y * bStrideB;
  const long db  = (long)blockIdx.y * bStrideD;
  const BT* bp = Bsrc + bb + n0;

  f32x4 acc[13];
#pragma unroll
  for (int t = 0; t < 13; ++t)
#pragma unroll
    for (int q = 0; q < 4; ++q) acc[t][q] = 0.f;

  int4 ar0, ar1, ar2, ar3;
  using BReg = std::conditional_t<BF32, f32x8, ushort8>;
  BReg B0, B1, B2, B3, B4, B5, B6;

  // prologue: A-slice 0 + ALL B loads; single drain at first barrier
  ALOAD(0)
  LOADB(0, B0) LOADB(1, B1) LOADB(2, B2) LOADB(3, B3)
  LOADB(4, B4) LOADB(5, B5) LOADB(6, B6)
  ASTORE(0)
  __syncthreads();

  ALOAD(1)  STAGE(0, B0)  ASTORE(1)  __syncthreads();
  ALOAD(2)  STAGE(1, B1)  ASTORE(0)  __syncthreads();
  ALOAD(3)  STAGE(2, B2)  ASTORE(1)  __syncthreads();
  ALOAD(4)  STAGE(3, B3)  ASTORE(0)  __syncthreads();
  ALOAD(5)  STAGE(4, B4)  ASTORE(1)  __syncthreads();
  ALOAD(6)  STAGE(5, B5)  ASTORE(0)  __syncthreads();
  STAGE(6, B6)

#pragma unroll
  for (int t = 0; t < 13; ++t) {
    const int rb = t * 16 + kg * 4;
#pragma unroll
    for (int r = 0; r < 4; ++r) {
      const int row = rb + r;
      if (row < N12) {
        if constexpr (std::is_same_v<DT, float>)
          Dout[db + (long)row * ldD + n0] = acc[t][r];
        else
          Dout[db + (long)row * ldD + n0] =
              __builtin_bit_cast(u16, (_Float16)acc[t][r]);
      }
    }
  }
}

// ------- contract k + elementwise, MFMA form (fp16 T2 input) --------------
// Per wave: one ab. D[s,c] = sum_k T2[ab,k,s]*K3[c,k]; B = K3B frags (LDS).
// D lane layout -> lane's 4 acc values s-contiguous => dwordx4 TT/reg.
__global__ __launch_bounds__(256, 8) void k_contract_k_mfma(
    const u16* __restrict__ T2h, const float* __restrict__ TT,
    const u16* __restrict__ K3B, float* __restrict__ reg) {
  __shared__ __align__(16) u16 bs[K3B_HALVES];   // 8 KB
  const int tid  = threadIdx.x;
  {
    const int4* src = (const int4*)K3B;
    int4* dst = (int4*)bs;
    dst[tid] = src[tid];
    dst[tid + 256] = src[tid + 256];
  }
  const int lane = tid & 63;
  const int wave = tid >> 6;
  const int l15  = lane & 15;
  const int kg   = lane >> 4;
  const int ab   = blockIdx.x * 4 + wave;         // 0..39999
  const int base = ab * SKS;
  __syncthreads();

  half8 bf[2][4];
#pragma unroll
  for (int ks = 0; ks < 2; ++ks)
#pragma unroll
    for (int cs = 0; cs < 4; ++cs)
      bf[ks][cs] = *(const half8*)(bs + ((ks * 4 + cs) * 64 + lane) * 8);

  // A fragments: fp16 direct. k clamped (B rows >= 50 are zero-padded).
  half8 af[2][2];
#pragma unroll
  for (int rt = 0; rt < 2; ++rt)
#pragma unroll
    for (int ks = 0; ks < 2; ++ks)
#pragma unroll
      for (int e = 0; e < 8; ++e) {
        int k = ks * 32 + kg * 8 + e; if (k > 49) k = 49;
        af[rt][ks][e] =
            __builtin_bit_cast(_Float16, T2h[base + k * R2 + rt * 16 + l15]);
      }

  f32x4 acc[2][4];
#pragma unroll
  for (int rt = 0; rt < 2; ++rt)
#pragma unroll
    for (int cs = 0; cs < 4; ++cs)
#pragma unroll
      for (int q = 0; q < 4; ++q) acc[rt][cs][q] = 0.f;

#pragma unroll
  for (int rt = 0; rt < 2; ++rt)
#pragma unroll
    for (int ks = 0; ks < 2; ++ks)
#pragma unroll
      for (int cs = 0; cs < 4; ++cs)
        acc[rt][cs] = __builtin_amdgcn_mfma_f32_16x16x32_f16(
            af[rt][ks], bf[ks][cs], acc[rt][cs], 0, 0, 0);

  // epilogue: c = cs*16+l15 (valid < 50), s0 = rt*16+kg*4; dwordx4 TT+store
#pragma unroll
  for (int rt = 0; rt < 2; ++rt)
#pragma unroll
    for (int cs = 0; cs < 4; ++cs) {
      const int c = cs * 16 + l15;
      if (c < N3) {
        const int o = base + c * R2 + rt * 16 + kg * 4;
        f32x4 tv = *(const f32x4*)(TT + o);
        f32x4 r;
#pragma unroll
        for (int q = 0; q < 4; ++q) r[q] = acc[rt][cs][q] * tv[q];
        *(f32x4*)(reg + o) = r;
      }
    }
}

// ------------- gather: out[n,s] = sum_k K3[c,k] * T2[a,b,k,s]  (a,b,c < 50)
template <typename T>
__global__ __launch_bounds__(256) void k_gather(
    const T* T2, const float* __restrict__ K3,
    const int* __restrict__ idx, float* __restrict__ out) {
  int g = blockIdx.x * 256 + threadIdx.x;   // 3.2M threads exactly
  int n = g >> 5, s = g & 31;
  int a = idx[n * 3 + 0], b = idx[n * 3 + 1], c = idx[n * 3 + 2];
  const T* t2 = T2 + a * SJK + b * SKS + s;
  const float* k3r = K3 + c * N3;
  float acc = 0.f;
#pragma unroll
  for (int k = 0; k < N3; ++k) {
    float v;
    if constexpr (std::is_same_v<T, float>) v = t2[k * R2];
    else v = (float)__builtin_bit_cast(_Float16, t2[k * R2]);
    acc = fmaf(k3r[k], v, acc);
  }
  out[g] = acc;
}

// ---------------- fallback path helpers (unused when ws >= 128 MB) ---------
__global__ __launch_bounds__(256) void k_transpose(
    const float* __restrict__ K2, float* __restrict__ K2T) {
  int t = blockIdx.x * 256 + threadIdx.x;
  if (t < N12 * N12) {
    int i = t / N12, a = t % N12;
    K2T[t] = K2[a * N12 + i];
  }
}

__global__ __launch_bounds__(256) void k_contract_j_inplace(
    float* T12, const float* __restrict__ K2T) {
  __shared__ float lds[N12 * 80];   // 64000 B
  const int a    = blockIdx.y;
  const int m0   = blockIdx.x * 80;
  const int base = a * SJK + m0;
  for (int t = threadIdx.x; t < N12 * 80; t += 256) {
    int j = t / 80, ml = t % 80;
    lds[t] = T12[base + j * SKS + ml];
  }
  __syncthreads();
  for (int o = threadIdx.x; o < N12 * 80; o += 256) {
    int b = o / 80, ml = o % 80;
    float acc = 0.f;
#pragma unroll 4
    for (int j = 0; j < N12; ++j)
      acc = fmaf(K2T[j * N12 + b], lds[j * 80 + ml], acc);
    T12[base + b * SKS + ml] = acc;
  }
}

__global__ __launch_bounds__(256) void k_contract_k_reg(
    const float* T2, const float* __restrict__ TT,
    const float* __restrict__ K3, float* reg) {
  const int t  = blockIdx.x * 256 + threadIdx.x;
  const int s  = t & 31;
  const int ab = t >> 5;
  const int base = ab * SKS + s;
  float v[N3];
#pragma unroll
  for (int k = 0; k < N3; ++k) v[k] = T2[base + k * R2];
  for (int c = 0; c < N3; ++c) {
    const float* k3r = K3 + c * N3;
    float a0 = 0.f, a1 = 0.f, a2 = 0.f, a3 = 0.f;
#pragma unroll
    for (int k = 0; k < 48; k += 4) {
      a0 = fmaf(k3r[k],     v[k],     a0);
      a1 = fmaf(k3r[k + 1], v[k + 1], a1);
      a2 = fmaf(k3r[k + 2], v[k + 2], a2);
      a3 = fmaf(k3r[k + 3], v[k + 3], a3);
    }
    a0 = fmaf(k3r[48], v[48], a0);
    a1 = fmaf(k3r[49], v[49], a1);
    const int o = base + c * R2;
    reg[o] = ((a0 + a1) + (a2 + a3)) * TT[o];
  }
}

extern "C" void kernel_launch(void* const* d_in, const int* in_sizes, int n_in,
                              void* d_out, int out_size, void* d_ws, size_t ws_size,
                              hipStream_t stream) {
  const float* TT  = (const float*)d_in[0];
  const float* K1  = (const float*)d_in[1];
  const float* K2  = (const float*)d_in[2];
  const float* K3  = (const float*)d_in[3];
  const int*   idx = (const int*)d_in[4];

  float* out = (float*)d_out;          // [0, 3.2M)
  float* reg = out + OUT_ELEMS;        // [3.2M, 67.2M) -- also T1h scratch
  // Prepped fp16 K matrices + K3B fragment pack live at the start of the out
  // region (dead before k_gather overwrites out). A-staging overruns read a
  // few KB past kh -- still inside d_out, benign.
  u16* kh = (u16*)d_out;
  const int matoff = APAD * KPAD;               // K2 offset within kh
  const u16* k3b = kh + 2 * matoff;             // K3B offset

  k_prep<<<dim3((2 * matoff + K3B_HALVES + 255) / 256), 256, 0, stream>>>(
      K1, K2, K3, kh);

  const size_t need = (size_t)NTOT * sizeof(u16);   // 128,000,000 B
  if (ws_size >= need) {
    u16* T1h = (u16*)reg;          // 128 MB in reg region (dead before ck)
    u16* T2h = (u16*)d_ws;         // 128 MB
    // contract i: T1h[a,m] = sum_i K1[a,i]*TT[i,m]
    k_mfma_contract<float, u16><<<dim3(SJK / 64, 1), 256, 0, stream>>>(
        TT, kh, T1h, SJK, SJK, 0L, 0L);
    // contract j (batched over a): T2h[a,b,m2] = sum_j K2[b,j]*T1h[a,j,m2]
    k_mfma_contract<u16, u16><<<dim3(SKS / 64, N12), 256, 0, stream>>>(
        T1h, kh + matoff, T2h, SKS, SKS, (long)SJK, (long)SJK);
    // contract k (writes reg fp32 over T1h region -- T1 dead; K3B still live)
    k_contract_k_mfma<<<dim3(40000 / 4), 256, 0, stream>>>(T2h, TT, k3b, reg);
    // gather last (clobbers kh/k3b region)
    k_gather<u16><<<dim3(OUT_ELEMS / 256), 256, 0, stream>>>(T2h, K3, idx, out);
  } else {
    // fp32 fallback (never taken on this harness: rounds 1-8 ran ws path)
    float* k2t = out + 2 * OUT_ELEMS / 32;  // scratch inside out region
    k_mfma_contract<float, float><<<dim3(SJK / 64, 1), 256, 0, stream>>>(
        TT, kh, reg, SJK, SJK, 0L, 0L);
    k_transpose<<<dim3((N12 * N12 + 255) / 256), 256, 0, stream>>>(K2, k2t);
    k_contract_j_inplace<<<dim3(20, N12), 256, 0, stream>>>(reg, k2t);
    k_gather<float><<<dim3(OUT_ELEMS / 256), 256, 0, stream>>>(reg, K3, idx, out);
    k_contract_k_reg<<<dim3(40000 * 32 / 256), 256, 0, stream>>>(reg, TT, K3, reg);
  }
}

// Round 10
// 403.035 us; speedup vs baseline: 1.2876x; 1.1061x over previous
//
#include <hip/hip_runtime.h>
#include <type_traits>

// Problem constants (from reference):
//   B=100000, R1=1, N1=200, N2=200, N3=50, R2=32
//   TT_core: (1,200,200,50,32) f32  = 64,000,000 elems (256 MB)
//   K1,K2: (200,200) f32; K3: (50,50) f32; indices: (B,3) int (values in [0,50))
//   out = (T3 gathered)[B,1,32] (3.2M f32), reg = T3*TT (64M f32)
// d_out layout: [0,3.2M) out, [3.2M, 67.2M) reg.
//
// Round-10: ck epilogue write-combining fix. Round-9 evidence: WRITE_SIZE
// 421 MB vs 256 ideal (1.64x amplification) because the two 64B halves of
// each 128B reg-line were stored far apart (rt-outer loop) -> L2 evicted
// half-dirty lines. Now cs-outer, both rt halves stored back-to-back.

typedef float    f32x4 __attribute__((ext_vector_type(4)));
typedef float    f32x8 __attribute__((ext_vector_type(8)));
typedef _Float16 half8 __attribute__((ext_vector_type(8)));
typedef unsigned short ushort8 __attribute__((ext_vector_type(8)));
typedef unsigned short u16;
typedef unsigned int   u32;

#define N12   200
#define N3    50
#define R2    32
#define SJK   320000          // stride of i in TT == N2*N3*R2; also stride of a in T1
#define SKS   1600            // stride of j / b  == N3*R2
#define NTOT  64000000
#define OUT_ELEMS 3200000     // B*32
#define APAD  208             // padded rows of K matrices (13 * 16)
#define KPAD  224             // padded contraction dim (7 * 32)
#define K3B_HALVES 4096       // 2 kstep * 4 csub * 64 lane * 8 e

// ---------------- prep: K1,K2 -> padded fp16 [208][224]; K3 -> B-frag pack --
// kh: K1 at 0, K2 at APAD*KPAD, K3B (fragment-ordered fp16) at 2*APAD*KPAD.
__global__ __launch_bounds__(256) void k_prep(
    const float* __restrict__ K1, const float* __restrict__ K2,
    const float* __restrict__ K3, u16* __restrict__ kh) {
  int t = blockIdx.x * 256 + threadIdx.x;
  const int total = APAD * KPAD;
  if (t >= 2 * total + K3B_HALVES) return;
  float x;
  if (t < 2 * total) {
    const float* src = (t < total) ? K1 : K2;
    int tt = (t < total) ? t : t - total;
    int r = tt / KPAD, c = tt % KPAD;
    x = (r < N12 && c < N12) ? src[r * N12 + c] : 0.f;
  } else {
    int u = t - 2 * total;
    int e = u & 7, l = (u >> 3) & 63, frag = u >> 9;   // frag = kstep*4+csub
    int c = (frag & 3) * 16 + (l & 15);
    int k = (frag >> 2) * 32 + (l >> 4) * 8 + e;
    x = (c < N3 && k < N3) ? K3[c * N3 + k] : 0.f;
  }
  kh[t] = __builtin_bit_cast(u16, (_Float16)x);
}

// ---------------- MFMA contraction: D[row,n] = sum_k K[row,k] * B[k,n] -----
// Templated on B element type (float: cvt at stage; u16: raw fp16) and D
// element type (float / u16-fp16 store). A via LDS dbuf (lgkmcnt), B fully
// prefetched in regs (single vmcnt drain) -- round-7 structure.
#define ALOAD(S)                                                              \
  { ar0 = *(const int4*)(Ah + ((wave*4+0)*16 + arow) * KPAD + (S)*32 + acolh); \
    ar1 = *(const int4*)(Ah + ((wave*4+1)*16 + arow) * KPAD + (S)*32 + acolh); \
    ar2 = *(const int4*)(Ah + ((wave*4+2)*16 + arow) * KPAD + (S)*32 + acolh); \
    ar3 = *(const int4*)(Ah + ((wave*4+3)*16 + arow) * KPAD + (S)*32 + acolh); }

#define ASTORE(BUF)                                                           \
  { *(int4*)(&As[BUF][(wave*4+0)*512 + lane*8]) = ar0;                        \
    *(int4*)(&As[BUF][(wave*4+1)*512 + lane*8]) = ar1;                        \
    *(int4*)(&As[BUF][(wave*4+2)*512 + lane*8]) = ar2;                        \
    *(int4*)(&As[BUF][(wave*4+3)*512 + lane*8]) = ar3; }

#define LOADB(S, BV)                                                          \
  { _Pragma("unroll")                                                         \
    for (int e = 0; e < 8; ++e) {                                             \
      int kr = (S)*32 + kq + e; if (kr > 199) kr = 199;                       \
      BV[e] = bp[(long)kr * ldB]; } }

#define STAGE(S, BV)                                                          \
  { half8 bh;                                                                 \
    _Pragma("unroll")                                                         \
    for (int e = 0; e < 8; ++e) {                                             \
      if constexpr (BF32) bh[e] = (_Float16)BV[e];                            \
      else bh[e] = __builtin_bit_cast(_Float16, (u16)BV[e]);                  \
    }                                                                         \
    const u16* as_ = &As[(S)&1][0];                                           \
    _Pragma("unroll")                                                         \
    for (int t = 0; t < 13; ++t) {                                            \
      half8 ah = *(const half8*)(as_ + (t*16 + l15)*32 + kq);                 \
      acc[t] = __builtin_amdgcn_mfma_f32_16x16x32_f16(ah, bh, acc[t], 0,0,0); \
    } }

template <typename BT, typename DT>
__global__ __launch_bounds__(256, 3) void k_mfma_contract(
    const BT* __restrict__ Bsrc, const u16* __restrict__ Ah,
    DT* __restrict__ Dout, int ldB, int ldD, long bStrideB, long bStrideD) {
  constexpr bool BF32 = std::is_same_v<BT, float>;
  __shared__ __align__(16) u16 As[2][8192];   // 2 x 16 KB
  const int lane = threadIdx.x & 63;
  const int wave = threadIdx.x >> 6;
  const int l15  = lane & 15;
  const int kg   = lane >> 4;
  const int kq   = kg * 8;
  const int arow = lane >> 2;           // 0..15 within a 16-row chunk
  const int acolh = (lane & 3) * 8;     // halves
  const int n0   = blockIdx.x * 64 + wave * 16 + l15;
  const long bb  = (long)blockIdx.y * bStrideB;
  const long db  = (long)blockIdx.y * bStrideD;
  const BT* bp = Bsrc + bb + n0;

  f32x4 acc[13];
#pragma unroll
  for (int t = 0; t < 13; ++t)
#pragma unroll
    for (int q = 0; q < 4; ++q) acc[t][q] = 0.f;

  int4 ar0, ar1, ar2, ar3;
  using BReg = std::conditional_t<BF32, f32x8, ushort8>;
  BReg B0, B1, B2, B3, B4, B5, B6;

  // prologue: A-slice 0 + ALL B loads; single drain at first barrier
  ALOAD(0)
  LOADB(0, B0) LOADB(1, B1) LOADB(2, B2) LOADB(3, B3)
  LOADB(4, B4) LOADB(5, B5) LOADB(6, B6)
  ASTORE(0)
  __syncthreads();

  ALOAD(1)  STAGE(0, B0)  ASTORE(1)  __syncthreads();
  ALOAD(2)  STAGE(1, B1)  ASTORE(0)  __syncthreads();
  ALOAD(3)  STAGE(2, B2)  ASTORE(1)  __syncthreads();
  ALOAD(4)  STAGE(3, B3)  ASTORE(0)  __syncthreads();
  ALOAD(5)  STAGE(4, B4)  ASTORE(1)  __syncthreads();
  ALOAD(6)  STAGE(5, B5)  ASTORE(0)  __syncthreads();
  STAGE(6, B6)

#pragma unroll
  for (int t = 0; t < 13; ++t) {
    const int rb = t * 16 + kg * 4;
#pragma unroll
    for (int r = 0; r < 4; ++r) {
      const int row = rb + r;
      if (row < N12) {
        if constexpr (std::is_same_v<DT, float>)
          Dout[db + (long)row * ldD + n0] = acc[t][r];
        else
          Dout[db + (long)row * ldD + n0] =
              __builtin_bit_cast(u16, (_Float16)acc[t][r]);
      }
    }
  }
}

// ------- contract k + elementwise, MFMA form (fp16 T2 input) --------------
// Per wave: one ab. D[s,c] = sum_k T2[ab,k,s]*K3[c,k]; B = K3B frags (LDS).
// Epilogue: cs OUTER, both rt halves of each 128B line stored back-to-back
// (round-9: rt-outer spread the halves -> 1.64x write amplification).
__global__ __launch_bounds__(256, 8) void k_contract_k_mfma(
    const u16* __restrict__ T2h, const float* __restrict__ TT,
    const u16* __restrict__ K3B, float* __restrict__ reg) {
  __shared__ __align__(16) u16 bs[K3B_HALVES];   // 8 KB
  const int tid  = threadIdx.x;
  {
    const int4* src = (const int4*)K3B;
    int4* dst = (int4*)bs;
    dst[tid] = src[tid];
    dst[tid + 256] = src[tid + 256];
  }
  const int lane = tid & 63;
  const int wave = tid >> 6;
  const int l15  = lane & 15;
  const int kg   = lane >> 4;
  const int ab   = blockIdx.x * 4 + wave;         // 0..39999
  const int base = ab * SKS;
  __syncthreads();

  half8 bf[2][4];
#pragma unroll
  for (int ks = 0; ks < 2; ++ks)
#pragma unroll
    for (int cs = 0; cs < 4; ++cs)
      bf[ks][cs] = *(const half8*)(bs + ((ks * 4 + cs) * 64 + lane) * 8);

  // A fragments: fp16 direct. k clamped (B rows >= 50 are zero-padded).
  half8 af[2][2];
#pragma unroll
  for (int rt = 0; rt < 2; ++rt)
#pragma unroll
    for (int ks = 0; ks < 2; ++ks)
#pragma unroll
      for (int e = 0; e < 8; ++e) {
        int k = ks * 32 + kg * 8 + e; if (k > 49) k = 49;
        af[rt][ks][e] =
            __builtin_bit_cast(_Float16, T2h[base + k * R2 + rt * 16 + l15]);
      }

  f32x4 acc[2][4];
#pragma unroll
  for (int rt = 0; rt < 2; ++rt)
#pragma unroll
    for (int cs = 0; cs < 4; ++cs)
#pragma unroll
      for (int q = 0; q < 4; ++q) acc[rt][cs][q] = 0.f;

#pragma unroll
  for (int rt = 0; rt < 2; ++rt)
#pragma unroll
    for (int ks = 0; ks < 2; ++ks)
#pragma unroll
      for (int cs = 0; cs < 4; ++cs)
        acc[rt][cs] = __builtin_amdgcn_mfma_f32_16x16x32_f16(
            af[rt][ks], bf[ks][cs], acc[rt][cs], 0, 0, 0);

  // epilogue: c = cs*16+l15 (valid < 50); per c, the full 128B line
  // (s 0..31) is covered by two adjacent dwordx4 stores (rt=0: kg*4, rt=1:
  // 16+kg*4) issued back-to-back so the line is fully dirty before eviction.
#pragma unroll
  for (int cs = 0; cs < 4; ++cs) {
    const int c = cs * 16 + l15;
    if (c < N3) {
      const int o0 = base + c * R2 + kg * 4;
      f32x4 tv0 = *(const f32x4*)(TT + o0);
      f32x4 tv1 = *(const f32x4*)(TT + o0 + 16);
      f32x4 r0, r1;
#pragma unroll
      for (int q = 0; q < 4; ++q) {
        r0[q] = acc[0][cs][q] * tv0[q];
        r1[q] = acc[1][cs][q] * tv1[q];
      }
      *(f32x4*)(reg + o0) = r0;
      *(f32x4*)(reg + o0 + 16) = r1;
    }
  }
}

// ------------- gather: out[n,s] = sum_k K3[c,k] * T2[a,b,k,s]  (a,b,c < 50)
template <typename T>
__global__ __launch_bounds__(256) void k_gather(
    const T* T2, const float* __restrict__ K3,
    const int* __restrict__ idx, float* __restrict__ out) {
  int g = blockIdx.x * 256 + threadIdx.x;   // 3.2M threads exactly
  int n = g >> 5, s = g & 31;
  int a = idx[n * 3 + 0], b = idx[n * 3 + 1], c = idx[n * 3 + 2];
  const T* t2 = T2 + a * SJK + b * SKS + s;
  const float* k3r = K3 + c * N3;
  float acc = 0.f;
#pragma unroll
  for (int k = 0; k < N3; ++k) {
    float v;
    if constexpr (std::is_same_v<T, float>) v = t2[k * R2];
    else v = (float)__builtin_bit_cast(_Float16, t2[k * R2]);
    acc = fmaf(k3r[k], v, acc);
  }
  out[g] = acc;
}

// ---------------- fallback path helpers (unused when ws >= 128 MB) ---------
__global__ __launch_bounds__(256) void k_transpose(
    const float* __restrict__ K2, float* __restrict__ K2T) {
  int t = blockIdx.x * 256 + threadIdx.x;
  if (t < N12 * N12) {
    int i = t / N12, a = t % N12;
    K2T[t] = K2[a * N12 + i];
  }
}

__global__ __launch_bounds__(256) void k_contract_j_inplace(
    float* T12, const float* __restrict__ K2T) {
  __shared__ float lds[N12 * 80];   // 64000 B
  const int a    = blockIdx.y;
  const int m0   = blockIdx.x * 80;
  const int base = a * SJK + m0;
  for (int t = threadIdx.x; t < N12 * 80; t += 256) {
    int j = t / 80, ml = t % 80;
    lds[t] = T12[base + j * SKS + ml];
  }
  __syncthreads();
  for (int o = threadIdx.x; o < N12 * 80; o += 256) {
    int b = o / 80, ml = o % 80;
    float acc = 0.f;
#pragma unroll 4
    for (int j = 0; j < N12; ++j)
      acc = fmaf(K2T[j * N12 + b], lds[j * 80 + ml], acc);
    T12[base + b * SKS + ml] = acc;
  }
}

__global__ __launch_bounds__(256) void k_contract_k_reg(
    const float* T2, const float* __restrict__ TT,
    const float* __restrict__ K3, float* reg) {
  const int t  = blockIdx.x * 256 + threadIdx.x;
  const int s  = t & 31;
  const int ab = t >> 5;
  const int base = ab * SKS + s;
  float v[N3];
#pragma unroll
  for (int k = 0; k < N3; ++k) v[k] = T2[base + k * R2];
  for (int c = 0; c < N3; ++c) {
    const float* k3r = K3 + c * N3;
    float a0 = 0.f, a1 = 0.f, a2 = 0.f, a3 = 0.f;
#pragma unroll
    for (int k = 0; k < 48; k += 4) {
      a0 = fmaf(k3r[k],     v[k],     a0);
      a1 = fmaf(k3r[k + 1], v[k + 1], a1);
      a2 = fmaf(k3r[k + 2], v[k + 2], a2);
      a3 = fmaf(k3r[k + 3], v[k + 3], a3);
    }
    a0 = fmaf(k3r[48], v[48], a0);
    a1 = fmaf(k3r[49], v[49], a1);
    const int o = base + c * R2;
    reg[o] = ((a0 + a1) + (a2 + a3)) * TT[o];
  }
}

extern "C" void kernel_launch(void* const* d_in, const int* in_sizes, int n_in,
                              void* d_out, int out_size, void* d_ws, size_t ws_size,
                              hipStream_t stream) {
  const float* TT  = (const float*)d_in[0];
  const float* K1  = (const float*)d_in[1];
  const float* K2  = (const float*)d_in[2];
  const float* K3  = (const float*)d_in[3];
  const int*   idx = (const int*)d_in[4];

  float* out = (float*)d_out;          // [0, 3.2M)
  float* reg = out + OUT_ELEMS;        // [3.2M, 67.2M) -- also T1h scratch
  // Prepped fp16 K matrices + K3B fragment pack live at the start of the out
  // region (dead before k_gather overwrites out). A-staging overruns read a
  // few KB past kh -- still inside d_out, benign.
  u16* kh = (u16*)d_out;
  const int matoff = APAD * KPAD;               // K2 offset within kh
  const u16* k3b = kh + 2 * matoff;             // K3B offset

  k_prep<<<dim3((2 * matoff + K3B_HALVES + 255) / 256), 256, 0, stream>>>(
      K1, K2, K3, kh);

  const size_t need = (size_t)NTOT * sizeof(u16);   // 128,000,000 B
  if (ws_size >= need) {
    u16* T1h = (u16*)reg;          // 128 MB in reg region (dead before ck)
    u16* T2h = (u16*)d_ws;         // 128 MB
    // contract i: T1h[a,m] = sum_i K1[a,i]*TT[i,m]
    k_mfma_contract<float, u16><<<dim3(SJK / 64, 1), 256, 0, stream>>>(
        TT, kh, T1h, SJK, SJK, 0L, 0L);
    // contract j (batched over a): T2h[a,b,m2] = sum_j K2[b,j]*T1h[a,j,m2]
    k_mfma_contract<u16, u16><<<dim3(SKS / 64, N12), 256, 0, stream>>>(
        T1h, kh + matoff, T2h, SKS, SKS, (long)SJK, (long)SJK);
    // contract k (writes reg fp32 over T1h region -- T1 dead; K3B still live)
    k_contract_k_mfma<<<dim3(40000 / 4), 256, 0, stream>>>(T2h, TT, k3b, reg);
    // gather last (clobbers kh/k3b region)
    k_gather<u16><<<dim3(OUT_ELEMS / 256), 256, 0, stream>>>(T2h, K3, idx, out);
  } else {
    // fp32 fallback (never taken on this harness: rounds 1-9 ran ws path)
    float* k2t = out + 2 * OUT_ELEMS / 32;  // scratch inside out region
    k_mfma_contract<float, float><<<dim3(SJK / 64, 1), 256, 0, stream>>>(
        TT, kh, reg, SJK, SJK, 0L, 0L);
    k_transpose<<<dim3((N12 * N12 + 255) / 256), 256, 0, stream>>>(K2, k2t);
    k_contract_j_inplace<<<dim3(20, N12), 256, 0, stream>>>(reg, k2t);
    k_gather<float><<<dim3(OUT_ELEMS / 256), 256, 0, stream>>>(reg, K3, idx, out);
    k_contract_k_reg<<<dim3(40000 * 32 / 256), 256, 0, stream>>>(reg, TT, K3, reg);
  }
}